// Round 9
// baseline (198.298 us; speedup 1.0000x reference)
//
#include <hip/hip_runtime.h>
#include <math.h>

#define Bb 8
#define Cc 128
#define Nn 3136                  // 56*56 real spatial
#define Np 3200                  // padded spatial (50 x 64)
#define NT 50                    // 64-row tiles per batch
#define NRT 49                   // real tiles (49*64 = 3136, no pad needed)
#define Mm (Bb*Cc*Nn)            // elements per output tensor
#define PADV 72                  // legacy s_pt row stride
#define L2E 1.44269504088896340736f
#define C44 (44.0f * L2E)        // shift 44 in log2 domain
#define ESCL 256.0f              // e quantization scale (i16; |e|<70 -> |q|<18k)
#define KDEC (L2E / 256.0f)      // decode: exponent = q * KDEC - c_i

// xt2: [b][T(50)][seg(16)][row(64)][8 u16]
#define XT2B (NT*16*64*8)
// xc2: [b][T(50)][seg(8)][c(128)][8 u16]
#define XC2B (NT*8*128*8)
// E: [b_][jt(49)][it(49)][jgrp(2)][s(4)][lane(64)][8 u16]  (i16 quantized e)
#define ETILE 4096               // u16 per (jt,it) tile = 8 KB
#define EBATCH ((size_t)NRT*NRT*ETILE)         // 9,834,496 u16 per batch
#define WS_BASE (131072 + 2*(size_t)Bb*XT2B*2) // row_d | xt2 | xc2

typedef unsigned short u16;
typedef unsigned int   u32;
typedef __attribute__((ext_vector_type(8)))  u16      u16x8;
typedef __attribute__((ext_vector_type(8)))  _Float16 f16x8;
typedef __attribute__((ext_vector_type(4)))  _Float16 f16x4;
typedef __attribute__((ext_vector_type(4)))  u32      u32x4;
typedef __attribute__((ext_vector_type(4)))  float    f32x4;
typedef __attribute__((ext_vector_type(16))) float    f32x16;

__device__ __forceinline__ float exp2fast(float x) {
#if __has_builtin(__builtin_amdgcn_exp2f)
    return __builtin_amdgcn_exp2f(x);
#else
    float r; asm("v_exp_f32 %0, %1" : "=v"(r) : "v"(x)); return r;
#endif
}

typedef __attribute__((address_space(1))) const unsigned int gas_u32;
typedef __attribute__((address_space(3))) unsigned int las_u32;
__device__ __forceinline__ void gload_lds16(const u16* g, u16* l) {
    __builtin_amdgcn_global_load_lds((gas_u32*)g, (las_u32*)l, 16, 0, 0);
}

#define BAR()    __builtin_amdgcn_s_barrier()
#define SCHED0() __builtin_amdgcn_sched_barrier(0)
#define W_ALL()  asm volatile("s_waitcnt vmcnt(0) lgkmcnt(0)" ::: "memory")

// pack two floats as i16 pair (lo = a): trunc quantization, |err| < 1/ESCL
__device__ __forceinline__ u32 pack_i16(float a, float b) {
    const int qa = (int)a, qb = (int)b;
    return (u32)(qa & 0xffff) | ((u32)qb << 16);
}

// ---------------------------------------------------------------------------
// Prep: x f32 -> fragment-major fp16 tiles xt2/xc2. Slot3 = gamma; x-copy in
// finish. grid 400 = 8 b * 50 n-blocks; nblk 49 zero-pads tile 49 (legacy).
// ---------------------------------------------------------------------------
__global__ __launch_bounds__(256) void prep_kernel(const float* __restrict__ x,
                                                   const float* __restrict__ gamma_p,
                                                   float* __restrict__ out,
                                                   u16* __restrict__ xt2,
                                                   u16* __restrict__ xc2,
                                                   float* __restrict__ row_d) {
    const int bx = blockIdx.x;
    const int b = bx / 50, nblk = bx % 50;
    const int t = threadIdx.x;

    if (nblk == 49) {            // pad tile: rows 3136..3199 all zero
        const u16x8 z8 = {0, 0, 0, 0, 0, 0, 0, 0};
        u16* dt = xt2 + ((size_t)b * NT + 49) * (16 * 64 * 8);
        u16* dc = xc2 + ((size_t)b * NT + 49) * (8 * 128 * 8);
        #pragma unroll
        for (int it = 0; it < 4; ++it) {
            *(u16x8*)&dt[(it * 256 + t) * 8] = z8;
            *(u16x8*)&dc[(it * 256 + t) * 8] = z8;
        }
        if (t < 64) row_d[b * Np + Nn + t] = 1.0f;
        return;
    }

    __shared__ float lx[Cc][65];
    const int n0 = nblk * 64;

    #pragma unroll 8
    for (int r = 0; r < 32; ++r) {
        const int c = r * 4 + (t >> 6);
        const int g = (b * Cc + c) * Nn + n0 + (t & 63);
        lx[c][t & 63] = x[g];
    }
    __syncthreads();

    {   // xt2
        const int nl = t & 63, cseg = t >> 6;
        u16x8 hv[4];
        #pragma unroll
        for (int cc = 0; cc < 32; ++cc) {
            const _Float16 hh = (_Float16)lx[cseg * 32 + cc][nl];
            hv[cc >> 3][cc & 7] = __builtin_bit_cast(u16, hh);
        }
        u16* base = xt2 + (((size_t)(b * NT + nblk) * 16 + cseg * 4) * 64 + nl) * 8;
        #pragma unroll
        for (int k = 0; k < 4; ++k) *(u16x8*)&base[k * (64 * 8)] = hv[k];
    }
    {   // xc2
        const int c = t >> 1, half = t & 1;
        u16x8 hv[4];
        #pragma unroll
        for (int k = 0; k < 32; ++k) {
            const _Float16 hh = (_Float16)lx[c][half * 32 + k];
            hv[k >> 3][k & 7] = __builtin_bit_cast(u16, hh);
        }
        u16* base = xc2 + (((size_t)(b * NT + nblk) * 8 + half * 4) * 128 + c) * 8;
        #pragma unroll
        for (int k = 0; k < 4; ++k) *(u16x8*)&base[k * (128 * 8)] = hv[k];
    }
    if (bx == 0 && t == 0) out[(size_t)3 * Mm] = gamma_p[0];
}

// ---------------------------------------------------------------------------
// E-kernel: energy D[m=i][n=j] (R3-verified orientation/pack), store E as
// i16-quantized MFMA-B-fragments; accumulate d_j = sum_i exp(e_ij-44)
// per-lane (row sums == col sums by symmetry of E). No LDS, no barriers.
// grid nb*196 = nb b * 49 jt * 4 iq (13/12/12/12 i-tiles).
// ---------------------------------------------------------------------------
__global__ __launch_bounds__(256, 4) void e_kernel(const u16* __restrict__ xt2,
                                                   u16* __restrict__ E,
                                                   float* __restrict__ row_d,
                                                   int bofs, int nb) {
    const int bx = blockIdx.x;
    const int b_ = bx % nb, rem = bx / nb;
    const int jt = rem >> 2, iq = rem & 3;
    const int b = bofs + b_;
    const int t = threadIdx.x;
    const int w = t >> 6, l = t & 63, lane = l & 31, h = l >> 5;
    const int isub = w & 1, jgrp = w >> 1;
    const u16* __restrict__ xb = xt2 + (size_t)b * XT2B;

    f16x8 Bj[8];                                 // resident j-row frags, seg 2kk+h
    const int jrow = jgrp * 32 + lane;
    #pragma unroll
    for (int kk = 0; kk < 8; ++kk)
        Bj[kk] = *(const f16x8*)&xb[(((size_t)jt * 16 + 2 * kk + h) * 64 + jrow) * 8];

    const int it0 = iq * 12 + (iq ? 1 : 0);      // 0,13,25,37
    const int icnt = iq ? 12 : 13;
    const int arow = isub * 32 + lane;

    float dA = 0.f, dB = 0.f;
    for (int it = it0; it < it0 + icnt; ++it) {
        const u16* ab = &xb[((size_t)it * 16 * 64 + arow) * 8];
        f32x16 ea;
        #pragma unroll
        for (int r = 0; r < 16; ++r) ea[r] = 0.f;
        __builtin_amdgcn_s_setprio(1);
        #pragma unroll
        for (int kk = 0; kk < 8; ++kk) {
            const f16x8 A = *(const f16x8*)&ab[(2 * kk + h) * 512];
            ea = __builtin_amdgcn_mfma_f32_32x32x16_f16(A, Bj[kk], ea, 0, 0, 0);
        }
        __builtin_amdgcn_s_setprio(0);

        const bool dt = (it == jt) && (isub == jgrp);
        u32 pk[4][2], sw[4][2];
        #pragma unroll
        for (int qq = 0; qq < 4; ++qq) {
            float pv[4];
            #pragma unroll
            for (int r2 = 0; r2 < 4; ++r2) {
                const int m = qq * 8 + h * 4 + r2;
                float v = ea[qq * 4 + r2];
                if (dt && m == lane) v = 0.f;    // diag mask (pre-softmax 0)
                pv[r2] = v;
                const float e = exp2fast(fmaf(v, L2E, -C44));
                if (r2 & 1) dB += e; else dA += e;
            }
            pk[qq][0] = pack_i16(pv[0] * ESCL, pv[1] * ESCL);
            pk[qq][1] = pack_i16(pv[2] * ESCL, pv[3] * ESCL);
            sw[qq][0] = __shfl_xor(pk[qq][0], 32, 64);
            sw[qq][1] = __shfl_xor(pk[qq][1], 32, 64);
        }
        // assemble B-frags (R3-verified): frag kt elem e = i-row kt*16+h*8+e
        u16* eb = E + ((((size_t)(b_ * NRT + jt) * NRT + it) * 2 + jgrp) * 4) * 512;
        #pragma unroll
        for (int kt = 0; kt < 2; ++kt) {
            u32x4 bw;
            bw[0] = h ? sw[2 * kt + 1][0] : pk[2 * kt][0];
            bw[1] = h ? sw[2 * kt + 1][1] : pk[2 * kt][1];
            bw[2] = h ? pk[2 * kt + 1][0] : sw[2 * kt][0];
            bw[3] = h ? pk[2 * kt + 1][1] : sw[2 * kt][1];
            *(u32x4*)&eb[(isub * 2 + kt) * 512 + l * 8] = bw;
        }
    }
    float d = dA + dB;
    d += __shfl_xor(d, 32, 64);                  // combine h-halves (disjoint i)
    if (h == 0) atomicAdd(&row_d[b * Np + jt * 64 + jgrp * 32 + lane], d);
}

// ---------------------------------------------------------------------------
// Conv: row_d -> c_i = 44*log2e + log2(d_i).
// ---------------------------------------------------------------------------
__global__ __launch_bounds__(256) void conv_kernel(float* __restrict__ row_d) {
    const int i = blockIdx.x * 256 + threadIdx.x;
    row_d[i] = C44 + __log2f(row_d[i]);
}

// ---------------------------------------------------------------------------
// PV-kernel: out_partial[c][j] = sum_i V[c][i] * exp2(q_ij*KDEC - c_i).
// Pure GEMM: E streamed HBM->LDS (8 KB/tile dbuf, 1 barrier/tile), decoded
// in-register to MFMA B-frags (layout guaranteed by e_kernel's pack); V
// A-frags direct from L2 (R2-verified addressing). K = 3136 real i only —
// pads gone. grid nb*98 = nb b * 49 jt * 2 kh. Partials -> slots 0/1.
// ---------------------------------------------------------------------------
__global__ __launch_bounds__(256, 3) void pv_kernel(const u16* __restrict__ xc2,
                                                    const u16* __restrict__ E,
                                                    const float* __restrict__ row_c,
                                                    float* __restrict__ out,
                                                    int bofs, int nb) {
    __shared__ __align__(16) u16 s_e[2][ETILE];  // 2 x 8 KB

    const int bx = blockIdx.x;
    const int b_ = bx % nb, rem = bx / nb;
    const int jt = rem >> 1, kh = rem & 1;
    const int b = bofs + b_;
    const int it0 = kh ? 25 : 0, it1 = kh ? 49 : 25;
    const int t = threadIdx.x;
    const int w = t >> 6, l = t & 63, lane = l & 31, h = l >> 5;
    const int jg = w & 1, cp = w >> 1;
    const u16* __restrict__ xcb = xc2 + (size_t)b * XC2B;
    const u16* __restrict__ Eb = E + (size_t)(b_ * NRT + jt) * NRT * ETILE;

    f32x16 a0, a1;
    #pragma unroll
    for (int r = 0; r < 16; ++r) { a0[r] = 0.f; a1[r] = 0.f; }

    // stage one 8 KB E tile: 8 x 1 KB, wave w covers chunks 2w, 2w+1
    {
        const u16* gs = Eb + (size_t)it0 * ETILE + (w * 2) * 512 + l * 8;
        u16* ls = &s_e[0][(w * 2) * 512];
        gload_lds16(gs, ls);
        gload_lds16(gs + 512, ls + 512);
    }
    W_ALL(); BAR(); SCHED0();

    for (int it = it0; it < it1; ++it) {
        const int cur = (it - it0) & 1;
        if (it + 1 < it1) {                      // stage next (in flight all iter)
            const u16* gs = Eb + (size_t)(it + 1) * ETILE + (w * 2) * 512 + l * 8;
            u16* ls = &s_e[cur ^ 1][(w * 2) * 512];
            gload_lds16(gs, ls);
            gload_lds16(gs + 512, ls + 512);
        }

        // decode 4 E-frags -> P (f16 B-frags); k-slice s: i = it*64+s*16+h*8+e
        const float* cb = &row_c[b * Np + it * 64];
        f16x8 Bp[4];
        #pragma unroll
        for (int s = 0; s < 4; ++s) {
            const u16x8 ev = *(const u16x8*)&s_e[cur][(jg * 4 + s) * 512 + l * 8];
            const f32x4 cA = *(const f32x4*)&cb[s * 16 + h * 8];
            const f32x4 cB = *(const f32x4*)&cb[s * 16 + h * 8 + 4];
            float p[8];
            #pragma unroll
            for (int e = 0; e < 8; ++e) {
                const float f = (float)(short)ev[e];
                const float c = (e < 4) ? cA[e] : cB[e - 4];
                p[e] = exp2fast(fmaf(f, KDEC, -c));
            }
            u32x4 bw;
            bw[0] = __builtin_bit_cast(u32, __builtin_amdgcn_cvt_pkrtz(p[0], p[1]));
            bw[1] = __builtin_bit_cast(u32, __builtin_amdgcn_cvt_pkrtz(p[2], p[3]));
            bw[2] = __builtin_bit_cast(u32, __builtin_amdgcn_cvt_pkrtz(p[4], p[5]));
            bw[3] = __builtin_bit_cast(u32, __builtin_amdgcn_cvt_pkrtz(p[6], p[7]));
            Bp[s] = __builtin_bit_cast(f16x8, bw);
        }

        // PV MFMA: A = V frags (L2 direct, R2 addressing), K = 64 per tile
        __builtin_amdgcn_s_setprio(1);
        #pragma unroll
        for (int s = 0; s < 4; ++s) {
            const f16x8 Av0 = *(const f16x8*)&xcb[((size_t)(it * 8 + s * 2 + h) * 128 + cp * 64 + lane) * 8];
            const f16x8 Av1 = *(const f16x8*)&xcb[((size_t)(it * 8 + s * 2 + h) * 128 + cp * 64 + 32 + lane) * 8];
            a0 = __builtin_amdgcn_mfma_f32_32x32x16_f16(Av0, Bp[s], a0, 0, 0, 0);
            a1 = __builtin_amdgcn_mfma_f32_32x32x16_f16(Av1, Bp[s], a1, 0, 0, 0);
        }
        __builtin_amdgcn_s_setprio(0);

        W_ALL(); BAR(); SCHED0();                // stage landed; cur free
    }

    // epilogue: raw f32 partials -> slot kh
    #pragma unroll
    for (int r = 0; r < 16; ++r) {
        const int mrow = (r & 3) + 8 * (r >> 2) + 4 * h;
        const int jj = jt * 64 + jg * 32 + lane;
        const size_t p0 = (size_t)(b * Cc + cp * 64 + mrow) * Nn + jj;
        const size_t p1 = (size_t)(b * Cc + cp * 64 + 32 + mrow) * Nn + jj;
        out[(size_t)kh * Mm + p0] = a0[r];
        out[(size_t)kh * Mm + p1] = a1[r];
    }
}

// ---------------------------------------------------------------------------
// Finish: o = relu(p0 + p1); slot0 = gamma*o + x; slot1 = o; slot2 = x.
// ---------------------------------------------------------------------------
__global__ __launch_bounds__(256) void finish_kernel(const float* __restrict__ x,
                                                     const float* __restrict__ gamma_p,
                                                     float* __restrict__ out) {
    const float gamma = gamma_p[0];
    const size_t base = ((size_t)blockIdx.x * 256 + threadIdx.x) * 4;
    const f32x4 pa = *(const f32x4*)&out[base];
    const f32x4 pb = *(const f32x4*)&out[(size_t)Mm + base];
    const f32x4 xv = *(const f32x4*)&x[base];
    f32x4 yo, oo;
    #pragma unroll
    for (int r = 0; r < 4; ++r) {
        const float o = fmaxf(pa[r] + pb[r], 0.0f);
        oo[r] = o;
        yo[r] = fmaf(gamma, o, xv[r]);
    }
    *(f32x4*)&out[base] = yo;
    *(f32x4*)&out[(size_t)Mm + base] = oo;
    *(f32x4*)&out[(size_t)2 * Mm + base] = xv;
}

// ============================ legacy fallback ==============================
// (R6-verified pair, used only if ws_size is too small for E)
__global__ __launch_bounds__(256, 5) void stats_legacy(const u16* __restrict__ xt2,
                                                       float* __restrict__ row_d) {
    const int bx = blockIdx.x;
    const int b = bx & 7, rem = bx >> 3;
    const int i0t = rem >> 3, jq = rem & 7;
    const int t = threadIdx.x;
    const int w = t >> 6, l = t & 63, lane = l & 31, h = l >> 5;
    const int igrp = w & 1, jsub = w >> 1;
    const u16* __restrict__ xb = xt2 + (size_t)b * XT2B;

    f16x8 Bf[8];
    const int irow = igrp * 32 + lane;
    #pragma unroll
    for (int kk = 0; kk < 8; ++kk)
        Bf[kk] = *(const f16x8*)&xb[(((size_t)i0t * 16 + 2 * kk + h) * 64 + irow) * 8];

    const int jt0 = jq * 6 + (jq < 2 ? jq : 2);
    const int jcnt = 6 + (jq < 2 ? 1 : 0);
    const int jrow = jsub * 32 + lane;

    float sa = 0.f, sb = 0.f;
    for (int jt = jt0; jt < jt0 + jcnt; ++jt) {
        const u16* ab = &xb[((size_t)jt * 16 * 64 + jrow) * 8];
        f32x16 ea, eb;
        #pragma unroll
        for (int r = 0; r < 16; ++r) { ea[r] = 0.f; eb[r] = 0.f; }
        #pragma unroll
        for (int kk = 0; kk < 4; ++kk) {
            const f16x8 A0 = *(const f16x8*)&ab[(4 * kk + h) * 512];
            const f16x8 A1 = *(const f16x8*)&ab[(4 * kk + 2 + h) * 512];
            ea = __builtin_amdgcn_mfma_f32_32x32x16_f16(A0, Bf[2 * kk],     ea, 0, 0, 0);
            eb = __builtin_amdgcn_mfma_f32_32x32x16_f16(A1, Bf[2 * kk + 1], eb, 0, 0, 0);
        }
        const bool diag = (jt == i0t) && (jsub == igrp);
        #pragma unroll
        for (int r = 0; r < 16; ++r) {
            const int mrow = (r & 3) + 8 * (r >> 2) + 4 * h;
            float v = ea[r] + eb[r];
            if (diag && mrow == lane) v = 0.f;
            const float e = exp2fast(fmaf(v, L2E, -C44));
            if (r & 1) sb += e; else sa += e;
        }
    }
    float ssum = sa + sb;
    ssum += __shfl_xor(ssum, 32, 64);
    if (h == 0) atomicAdd(&row_d[b * Np + i0t * 64 + igrp * 32 + lane], ssum);
}

__global__ __launch_bounds__(256, 3) void out_legacy(const u16* __restrict__ xt2,
                                                     const u16* __restrict__ xc2,
                                                     const float* __restrict__ row_c,
                                                     float* __restrict__ out) {
    __shared__ u16 s_pt[2][64 * PADV];

    const int bx = blockIdx.x;
    const int b = bx & 7, rem = bx >> 3;
    const int j0t = rem >> 1, ih = rem & 1;
    const int ti0 = ih * 25, ti1 = ti0 + 25;
    const int t = threadIdx.x;
    const int w = t >> 6, l = t & 63, lane = l & 31, h = l >> 5;
    const int isub = w & 1, jgrp = w >> 1;
    const int jg = w & 1,  cp = w >> 1;
    const u16* __restrict__ xtb = xt2 + (size_t)b * XT2B;
    const u16* __restrict__ xcb = xc2 + (size_t)b * XC2B;

    f16x8 Bj[8];
    const int jrow = jgrp * 32 + lane;
    #pragma unroll
    for (int kk = 0; kk < 8; ++kk)
        Bj[kk] = *(const f16x8*)&xtb[(((size_t)j0t * 16 + 2 * kk + h) * 64 + jrow) * 8];

    f32x16 oa, ob;
    #pragma unroll
    for (int r = 0; r < 16; ++r) { oa[r] = 0.f; ob[r] = 0.f; }

    const int arow = isub * 32 + lane;
    const int ptbase = (jgrp * 32 + lane) * PADV + isub * 32;
    const int pbrow = (jg * 32 + lane) * PADV + h * 8;

    f16x8 Ac[8];
    {
        const u16* ab = &xtb[((size_t)ti0 * 16 * 64 + arow) * 8];
        #pragma unroll
        for (int kk = 0; kk < 8; ++kk)
            Ac[kk] = *(const f16x8*)&ab[(2 * kk + h) * 512];
    }

    for (int ti = ti0; ti < ti1; ++ti) {
        const int tn = (ti + 1 < ti1) ? ti + 1 : ti;
        f16x8 An[8];
        const u16* abn = &xtb[((size_t)tn * 16 * 64 + arow) * 8];
        #pragma unroll
        for (int kk = 0; kk < 8; ++kk)
            An[kk] = *(const f16x8*)&abn[(2 * kk + h) * 512];

        f32x16 ea;
        #pragma unroll
        for (int r = 0; r < 16; ++r) ea[r] = 0.f;
        #pragma unroll
        for (int kk = 0; kk < 8; ++kk)
            ea = __builtin_amdgcn_mfma_f32_32x32x16_f16(Ac[kk], Bj[kk], ea, 0, 0, 0);

        u16* pt = &s_pt[ti & 1][0];
        const float* cbase = &row_c[b * Np + ti * 64 + isub * 32];
        const bool dsub = (ti == j0t) && (isub == jgrp);
        #pragma unroll
        for (int qq = 0; qq < 4; ++qq) {
            const f32x4 cv = *(const f32x4*)&cbase[qq * 8 + h * 4];
            f16x4 pv;
            #pragma unroll
            for (int r = 0; r < 4; ++r) {
                const int m = qq * 8 + h * 4 + r;
                float v = ea[qq * 4 + r];
                if (dsub && m == lane) v = 0.f;
                pv[r] = (_Float16)exp2fast(fmaf(v, L2E, -cv[r]));
            }
            *(f16x4*)&pt[ptbase + qq * 8 + h * 4] = pv;
        }

        f16x8 Av[4][2];
        const u16* vb = &xcb[((size_t)ti * 8 * 128 + cp * 64 + lane) * 8];
        #pragma unroll
        for (int kk = 0; kk < 4; ++kk) {
            Av[kk][0] = *(const f16x8*)&vb[((2 * kk + h) * 128) * 8];
            Av[kk][1] = *(const f16x8*)&vb[((2 * kk + h) * 128 + 32) * 8];
        }
        __syncthreads();

        #pragma unroll
        for (int kk = 0; kk < 4; ++kk) {
            const f16x8 Bp = *(const f16x8*)&pt[pbrow + kk * 16];
            oa = __builtin_amdgcn_mfma_f32_32x32x16_f16(Av[kk][0], Bp, oa, 0, 0, 0);
            ob = __builtin_amdgcn_mfma_f32_32x32x16_f16(Av[kk][1], Bp, ob, 0, 0, 0);
        }
        #pragma unroll
        for (int kk = 0; kk < 8; ++kk) Ac[kk] = An[kk];
    }

    #pragma unroll
    for (int r = 0; r < 16; ++r) {
        const int mrow = (r & 3) + 8 * (r >> 2) + 4 * h;
        const int jj = j0t * 64 + jg * 32 + lane;
        const size_t p0 = (size_t)(b * Cc + cp * 64 + mrow) * Nn + jj;
        const size_t p1 = (size_t)(b * Cc + cp * 64 + 32 + mrow) * Nn + jj;
        out[(size_t)ih * Mm + p0] = oa[r];
        out[(size_t)ih * Mm + p1] = ob[r];
    }
}

extern "C" void kernel_launch(void* const* d_in, const int* in_sizes, int n_in,
                              void* d_out, int out_size, void* d_ws, size_t ws_size,
                              hipStream_t stream) {
    const float* x       = (const float*)d_in[0];
    const float* gamma_p = (const float*)d_in[1];
    float* out = (float*)d_out;

    float* row_d = (float*)d_ws;
    u16* xt2 = (u16*)((char*)d_ws + (1 << 17));
    u16* xc2 = xt2 + (size_t)Bb * XT2B;
    u16* E   = (u16*)((char*)d_ws + WS_BASE);
    const size_t ebytes1 = EBATCH * 2;           // bytes of E per batch

    hipMemsetAsync(row_d, 0, (size_t)Bb * Np * sizeof(float), stream);
    prep_kernel<<<400, 256, 0, stream>>>(x, gamma_p, out, xt2, xc2, row_d);

    int nb = 0;                                  // batches per chunk
    if      (ws_size >= WS_BASE + 8 * ebytes1) nb = 8;
    else if (ws_size >= WS_BASE + 4 * ebytes1) nb = 4;
    else if (ws_size >= WS_BASE + 2 * ebytes1) nb = 2;

    if (nb) {
        for (int bofs = 0; bofs < Bb; bofs += nb) {
            e_kernel <<<nb * 196, 256, 0, stream>>>(xt2, E, row_d, bofs, nb);
            conv_kernel<<<(nb * Np) / 256, 256, 0, stream>>>(row_d + (size_t)bofs * Np);
            pv_kernel<<<nb * 98, 256, 0, stream>>>(xc2, E, row_d, out, bofs, nb);
        }
    } else {                                     // legacy (R6-verified) path
        stats_legacy<<<3136, 256, 0, stream>>>(xt2, row_d);
        conv_kernel <<<100, 256, 0, stream>>>(row_d);
        out_legacy  <<<784, 256, 0, stream>>>(xt2, xc2, row_d, out);
    }
    finish_kernel<<<3136, 256, 0, stream>>>(x, gamma_p, out);
}